// Round 6
// baseline (215.216 us; speedup 1.0000x reference)
//
#include <hip/hip_runtime.h>

#define BB 2
#define SEQ 2048
#define DIM 768
#define NH 12
#define HD 64

typedef _Float16 half8 __attribute__((ext_vector_type(8)));
typedef float floatx4 __attribute__((ext_vector_type(4)));

// Async global->LDS DMA, 16 B per lane; LDS dest = wave-uniform base + lane*16.
__device__ __forceinline__ void gl_lds16(const _Float16* g, _Float16* l) {
    __builtin_amdgcn_global_load_lds(
        (const __attribute__((address_space(1))) void*)g,
        (__attribute__((address_space(3))) void*)l, 16, 0, 0);
}

// ---------------------------------------------------------------------------
// One-shot fp32 -> f16 convert for x, W_kqv, W_proj (block ranges).
// ---------------------------------------------------------------------------
__global__ __launch_bounds__(256)
void cvt3(const float* __restrict__ s0, _Float16* __restrict__ d0, int nb0,
          const float* __restrict__ s1, _Float16* __restrict__ d1, int nb1,
          const float* __restrict__ s2, _Float16* __restrict__ d2) {
    int b = blockIdx.x;
    const float* s; _Float16* d;
    if (b < nb0)            { s = s0; d = d0; }
    else if (b < nb0 + nb1) { s = s1; d = d1; b -= nb0; }
    else                    { s = s2; d = d2; b -= nb0 + nb1; }
    const int i = (b * 256 + threadIdx.x) * 8;
    float4 a = *(const float4*)(s + i);
    float4 c = *(const float4*)(s + i + 4);
    half8 h;
    h[0] = (_Float16)a.x; h[1] = (_Float16)a.y; h[2] = (_Float16)a.z; h[3] = (_Float16)a.w;
    h[4] = (_Float16)c.x; h[5] = (_Float16)c.y; h[6] = (_Float16)c.z; h[7] = (_Float16)c.w;
    *(half8*)(d + i) = h;
}

// ---------------------------------------------------------------------------
// m97-style GEMM core, NOW DOUBLE-BUFFERED: BM=BN=128, BK=32, 4 waves (2x2).
// Per K-step: one barrier; stage next tile into buf^1 (DMA flies under
// compute); 8 ds_read_b128 + 16 MFMA on buf.  LDS chunks fragment-ordered
// in DMA lane order -> conflict-free reads at base + lane*16.
// ---------------------------------------------------------------------------
#define GEMM_CORE(APTR, BPTR)                                                   \
    __shared__ _Float16 Asl[2][128 * 32];                                       \
    __shared__ _Float16 Bsl[2][128 * 32];                                       \
    const int t = threadIdx.x, w = t >> 6, lane = t & 63;                       \
    const int quad = lane >> 4, l15 = lane & 15;                                \
    const int wm = w >> 1, wn = w & 1;                                          \
    const int m0 = blockIdx.y * 128, c0 = blockIdx.x * 128;                     \
    const floatx4 z4 = {0.f, 0.f, 0.f, 0.f};                                    \
    floatx4 acc[4][4];                                                          \
    _Pragma("unroll") for (int i = 0; i < 4; ++i)                               \
        _Pragma("unroll") for (int j = 0; j < 4; ++j) acc[i][j] = z4;           \
    const _Float16* pA = APTR + (size_t)(m0 + w * 32 + l15) * DIM + quad * 8;   \
    const _Float16* pB = BPTR + (size_t)(c0 + w * 32 + l15) * DIM + quad * 8;   \
    gl_lds16(pA,            &Asl[0][(w * 2 + 0) * 512]);                        \
    gl_lds16(pA + 16 * DIM, &Asl[0][(w * 2 + 1) * 512]);                        \
    gl_lds16(pB,            &Bsl[0][(w * 2 + 0) * 512]);                        \
    gl_lds16(pB + 16 * DIM, &Bsl[0][(w * 2 + 1) * 512]);                        \
    for (int k0 = 0, it = 0; k0 < DIM; k0 += 32, ++it) {                        \
        const int buf = it & 1;                                                 \
        __syncthreads();                                                        \
        if (k0 + 32 < DIM) {                                                    \
            gl_lds16(pA + k0 + 32,            &Asl[buf ^ 1][(w * 2 + 0) * 512]);\
            gl_lds16(pA + k0 + 32 + 16 * DIM, &Asl[buf ^ 1][(w * 2 + 1) * 512]);\
            gl_lds16(pB + k0 + 32,            &Bsl[buf ^ 1][(w * 2 + 0) * 512]);\
            gl_lds16(pB + k0 + 32 + 16 * DIM, &Bsl[buf ^ 1][(w * 2 + 1) * 512]);\
        }                                                                       \
        half8 af[4], bf[4];                                                     \
        _Pragma("unroll") for (int i = 0; i < 4; ++i)                           \
            af[i] = *(const half8*)&Asl[buf][(wm * 4 + i) * 512 + lane * 8];    \
        _Pragma("unroll") for (int j = 0; j < 4; ++j)                           \
            bf[j] = *(const half8*)&Bsl[buf][(wn * 4 + j) * 512 + lane * 8];    \
        _Pragma("unroll") for (int i = 0; i < 4; ++i)                           \
            _Pragma("unroll") for (int j = 0; j < 4; ++j)                       \
                acc[i][j] = __builtin_amdgcn_mfma_f32_16x16x32_f16(             \
                    af[i], bf[j], acc[i][j], 0, 0, 0);                          \
    }

// KQV: N=2304 (18 blocks of 128), scatter epilogue into k/q/v f16 buffers.
__global__ __launch_bounds__(256)
void kqv_gemm2(const _Float16* __restrict__ xh, const _Float16* __restrict__ Wh,
               const float* __restrict__ bias, _Float16* __restrict__ kb,
               _Float16* __restrict__ qb, _Float16* __restrict__ vb) {
    GEMM_CORE(xh, Wh)
    #pragma unroll
    for (int j = 0; j < 4; ++j) {
        const int cbase = c0 + (wn * 4 + j) * 16;
        const int h = cbase / 192;
        const int rem = cbase - h * 192;
        const int part = rem >> 6;
        const int d = (rem & 63) + l15;
        _Float16* dst = (part == 0) ? kb : (part == 1 ? qb : vb);
        const float bv = bias[cbase + l15];
        #pragma unroll
        for (int i = 0; i < 4; ++i)
            #pragma unroll
            for (int r = 0; r < 4; ++r) {
                const int m = m0 + (wm * 4 + i) * 16 + quad * 4 + r;
                const int bidx = m >> 11, n = m & (SEQ - 1);
                dst[(((size_t)(bidx * NH + h) * SEQ + n) << 6) + d] =
                    (_Float16)(acc[i][j][r] + bv);
            }
    }
}

// Proj: N=768 (6 blocks of 128), fp32 output + bias.
__global__ __launch_bounds__(256)
void proj_gemm2(const _Float16* __restrict__ A, const _Float16* __restrict__ Wh,
                const float* __restrict__ bias, float* __restrict__ out) {
    GEMM_CORE(A, Wh)
    #pragma unroll
    for (int j = 0; j < 4; ++j) {
        const int cbase = c0 + (wn * 4 + j) * 16;
        const float bv = bias[cbase + l15];
        #pragma unroll
        for (int i = 0; i < 4; ++i)
            #pragma unroll
            for (int r = 0; r < 4; ++r) {
                const int m = m0 + (wm * 4 + i) * 16 + quad * 4 + r;
                out[(size_t)m * DIM + cbase + l15] = acc[i][j][r] + bv;
            }
    }
}

// ---------------------------------------------------------------------------
// V transpose: vb [B][H][SEQ][HD] -> vbT [B][H][HD][SEQ]  (f16)
// ---------------------------------------------------------------------------
__global__ __launch_bounds__(256)
void v_transpose(const _Float16* __restrict__ vb, _Float16* __restrict__ vbT) {
    __shared__ _Float16 T[64 * 72];
    const int t = threadIdx.x;
    const int s0 = blockIdx.x * 64;
    const size_t base = (size_t)blockIdx.y * (SEQ * HD);
    {
        const int s = t >> 2, doff = (t & 3) * 16;
        const _Float16* src = vb + base + (size_t)(s0 + s) * HD + doff;
        *(half8*)&T[s * 72 + doff]     = *(const half8*)src;
        *(half8*)&T[s * 72 + doff + 8] = *(const half8*)(src + 8);
    }
    __syncthreads();
    {
        const int d = t >> 2, soff = (t & 3) * 16;
        half8 o0, o1;
        #pragma unroll
        for (int k = 0; k < 8; ++k) o0[k] = T[(soff + k) * 72 + d];
        #pragma unroll
        for (int k = 0; k < 8; ++k) o1[k] = T[(soff + 8 + k) * 72 + d];
        _Float16* dst = vbT + base + (size_t)d * SEQ + s0 + soff;
        *(half8*)dst       = o0;
        *(half8*)(dst + 8) = o1;
    }
}

// ---------------------------------------------------------------------------
// Flash attention, MFMA.  NOW: 128 Q rows per block (wave w owns rows
// [w*32, w*32+32) = two 16-row tiles) -> 32 MFMAs per wave per barrier
// interval, half the staging traffic.  Descending-work launch order
// (Q = 15 - blockIdx.x) so the heaviest blocks dispatch first.
// Max-free softmax; per-wave P buffers; K/V double-buffered via async DMA.
// ---------------------------------------------------------------------------
__global__ __launch_bounds__(256)
void attn_mfma(const _Float16* __restrict__ qb, const _Float16* __restrict__ kbuf,
               const _Float16* __restrict__ vbT, _Float16* __restrict__ sa) {
    __shared__ _Float16 Kl[2][64 * 64];
    __shared__ _Float16 Vl[2][64 * 64];
    __shared__ _Float16 Pl[4][2][16 * 72];
    const int Q = 15 - blockIdx.x;        // heavy blocks first
    const int bh = blockIdx.y;
    const int t = threadIdx.x, w = t >> 6, lane = t & 63, quad = lane >> 4, l15 = lane & 15;
    const size_t base = (size_t)bh * (SEQ * HD);
    const int i0 = Q * 128 + w * 32;      // wave's first row
    const _Float16* Kg = kbuf + base;
    const _Float16* Vg = vbT + base;
    const int nkt = 2 * Q + 2;

    const int lr = lane >> 3, gg = lane & 7;
    const int gs = (gg ^ (lr & 7)) * 8;

    half8 aq[2][2];
    #pragma unroll
    for (int rt = 0; rt < 2; ++rt)
        #pragma unroll
        for (int ks = 0; ks < 2; ++ks) {
            aq[rt][ks] = *(const half8*)(qb + base +
                          (size_t)(i0 + rt * 16 + l15) * HD + ks * 32 + quad * 8);
            #pragma unroll
            for (int k = 0; k < 8; ++k)
                aq[rt][ks][k] = aq[rt][ks][k] * (_Float16)0.125f;  // 1/sqrt(HD)
        }

    const floatx4 z4 = {0.f, 0.f, 0.f, 0.f};
    floatx4 O[2][4];
    float l_part[2][4];
    #pragma unroll
    for (int rt = 0; rt < 2; ++rt)
        #pragma unroll
        for (int k = 0; k < 4; ++k) { O[rt][k] = z4; l_part[rt][k] = 0.f; }

    // prologue: stage tile kt=0 into buffer 0
    #pragma unroll
    for (int p = 0; p < 2; ++p) {
        const int c = w * 2 + p, row = c * 8 + lr;
        gl_lds16(Kg + (size_t)row * HD + gs,  &Kl[0][c * 512]);
        gl_lds16(Vg + (size_t)row * SEQ + gs, &Vl[0][c * 512]);
    }

    const int swz = l15 & 7;

    for (int kt = 0; kt < nkt; ++kt) {
        const int buf = kt & 1;
        const int j0 = kt * 64;
        __syncthreads();   // staging of `buf` drained; prev compute on buf^1 done

        if (kt + 1 < nkt) {
            const _Float16* Kn = Kg + (size_t)(j0 + 64) * HD;
            const _Float16* Vn = Vg + (j0 + 64);
            #pragma unroll
            for (int p = 0; p < 2; ++p) {
                const int c = w * 2 + p, row = c * 8 + lr;
                gl_lds16(Kn + (size_t)row * HD + gs,  &Kl[buf ^ 1][c * 512]);
                gl_lds16(Vn + (size_t)row * SEQ + gs, &Vl[buf ^ 1][c * 512]);
            }
        }
        if (j0 > i0 + 31) continue;   // tile fully masked for this wave

        floatx4 S[2][4];
        #pragma unroll
        for (int rt = 0; rt < 2; ++rt)
            #pragma unroll
            for (int nt = 0; nt < 4; ++nt) S[rt][nt] = z4;
        #pragma unroll
        for (int ks = 0; ks < 2; ++ks)
            #pragma unroll
            for (int nt = 0; nt < 4; ++nt) {
                half8 bk = *(const half8*)&Kl[buf][(nt * 16 + l15) * 64 +
                                                   (((ks * 4 + quad) ^ swz) << 3)];
                S[0][nt] = __builtin_amdgcn_mfma_f32_16x16x32_f16(aq[0][ks], bk, S[0][nt], 0, 0, 0);
                S[1][nt] = __builtin_amdgcn_mfma_f32_16x16x32_f16(aq[1][ks], bk, S[1][nt], 0, 0, 0);
            }

        const bool needmask = (j0 + 63 > i0);
        asm volatile("" ::: "memory");   // WAR: prior P-frag reads before new writes
        #pragma unroll
        for (int rt = 0; rt < 2; ++rt)
            #pragma unroll
            for (int nt = 0; nt < 4; ++nt) {
                const int j = j0 + nt * 16 + l15;
                #pragma unroll
                for (int r = 0; r < 4; ++r) {
                    float p = __expf(S[rt][nt][r]);
                    if (needmask && j > (i0 + rt * 16 + quad * 4 + r)) p = 0.f;
                    l_part[rt][r] += p;
                    Pl[w][rt][(quad * 4 + r) * 72 + nt * 16 + l15] = (_Float16)p;
                }
            }
        asm volatile("" ::: "memory");   // RAW: P writes before fragment reads
        #pragma unroll
        for (int ks = 0; ks < 2; ++ks) {
            half8 ap0 = *(const half8*)&Pl[w][0][l15 * 72 + ks * 32 + quad * 8];
            half8 ap1 = *(const half8*)&Pl[w][1][l15 * 72 + ks * 32 + quad * 8];
            #pragma unroll
            for (int dt = 0; dt < 4; ++dt) {
                half8 bv = *(const half8*)&Vl[buf][(dt * 16 + l15) * 64 +
                                                    (((ks * 4 + quad) ^ swz) << 3)];
                O[0][dt] = __builtin_amdgcn_mfma_f32_16x16x32_f16(ap0, bv, O[0][dt], 0, 0, 0);
                O[1][dt] = __builtin_amdgcn_mfma_f32_16x16x32_f16(ap1, bv, O[1][dt], 0, 0, 0);
            }
        }
    }

    const int bidx = bh / NH, h = bh - bidx * NH;
    #pragma unroll
    for (int rt = 0; rt < 2; ++rt)
        #pragma unroll
        for (int r = 0; r < 4; ++r) {
            float rs = l_part[rt][r];
            #pragma unroll
            for (int off = 1; off < 16; off <<= 1) rs += __shfl_xor(rs, off);
            const float inv = 1.0f / rs;
            const int i = i0 + rt * 16 + quad * 4 + r;
            #pragma unroll
            for (int dt = 0; dt < 4; ++dt)
                sa[(size_t)(bidx * SEQ + i) * DIM + h * HD + dt * 16 + l15] =
                    (_Float16)(O[rt][dt][r] * inv);
        }
}

// ---------------------------------------------------------------------------
extern "C" void kernel_launch(void* const* d_in, const int* in_sizes, int n_in,
                              void* d_out, int out_size, void* d_ws, size_t ws_size,
                              hipStream_t stream) {
    (void)in_sizes; (void)n_in; (void)out_size; (void)ws_size;
    const float* x  = (const float*)d_in[0];
    const float* Wk = (const float*)d_in[1];
    const float* bk = (const float*)d_in[2];
    const float* Wp = (const float*)d_in[3];
    const float* bp = (const float*)d_in[4];
    float* out = (float*)d_out;

    _Float16* ws = (_Float16*)d_ws;
    const size_t per = (size_t)BB * NH * SEQ * HD;          // 3,145,728 halves
    const int nx = BB * SEQ * DIM;                          // 3,145,728
    const int nwk = NH * 3 * HD * DIM;                      // 1,769,472
    _Float16* kb  = ws;
    _Float16* qb  = ws + per;
    _Float16* vb  = ws + 2 * per;
    _Float16* vbT = ws + 3 * per;
    _Float16* sa  = ws + 4 * per;
    _Float16* xh  = ws + 5 * per;
    _Float16* Wkh = xh + nx;
    _Float16* Wph = Wkh + nwk;

    const int nb0 = nx / 2048, nb1 = nwk / 2048, nb2 = (DIM * DIM) / 2048;
    cvt3<<<dim3(nb0 + nb1 + nb2), 256, 0, stream>>>(x, xh, nb0, Wk, Wkh, nb1, Wp, Wph);

    kqv_gemm2 <<<dim3(18, 32), 256, 0, stream>>>(xh, Wkh, bk, kb, qb, vb);
    v_transpose<<<dim3(32, 24), 256, 0, stream>>>(vb, vbT);
    attn_mfma <<<dim3(16, 24), 256, 0, stream>>>(qb, kb, vbT, sa);
    proj_gemm2<<<dim3(6, 32), 256, 0, stream>>>(sa, Wph, bp, out);
}

// Round 7
// 188.914 us; speedup vs baseline: 1.1392x; 1.1392x over previous
//
#include <hip/hip_runtime.h>

#define BB 2
#define SEQ 2048
#define DIM 768
#define NH 12
#define HD 64

typedef _Float16 half8 __attribute__((ext_vector_type(8)));
typedef float floatx4 __attribute__((ext_vector_type(4)));

// Async global->LDS DMA, 16 B per lane; LDS dest = wave-uniform base + lane*16.
__device__ __forceinline__ void gl_lds16(const _Float16* g, _Float16* l) {
    __builtin_amdgcn_global_load_lds(
        (const __attribute__((address_space(1))) void*)g,
        (__attribute__((address_space(3))) void*)l, 16, 0, 0);
}

// ---------------------------------------------------------------------------
// One-shot fp32 -> f16 convert for x, W_kqv, W_proj (block ranges).
// ---------------------------------------------------------------------------
__global__ __launch_bounds__(256)
void cvt3(const float* __restrict__ s0, _Float16* __restrict__ d0, int nb0,
          const float* __restrict__ s1, _Float16* __restrict__ d1, int nb1,
          const float* __restrict__ s2, _Float16* __restrict__ d2) {
    int b = blockIdx.x;
    const float* s; _Float16* d;
    if (b < nb0)            { s = s0; d = d0; }
    else if (b < nb0 + nb1) { s = s1; d = d1; b -= nb0; }
    else                    { s = s2; d = d2; b -= nb0 + nb1; }
    const int i = (b * 256 + threadIdx.x) * 8;
    float4 a = *(const float4*)(s + i);
    float4 c = *(const float4*)(s + i + 4);
    half8 h;
    h[0] = (_Float16)a.x; h[1] = (_Float16)a.y; h[2] = (_Float16)a.z; h[3] = (_Float16)a.w;
    h[4] = (_Float16)c.x; h[5] = (_Float16)c.y; h[6] = (_Float16)c.z; h[7] = (_Float16)c.w;
    *(half8*)(d + i) = h;
}

// ---------------------------------------------------------------------------
// Double-buffered m97-style GEMM core: BM=BN=128, BK=32, 4 waves (2x2).
// ---------------------------------------------------------------------------
#define GEMM_CORE(APTR, BPTR)                                                   \
    __shared__ _Float16 Asl[2][128 * 32];                                       \
    __shared__ _Float16 Bsl[2][128 * 32];                                       \
    const int t = threadIdx.x, w = t >> 6, lane = t & 63;                       \
    const int quad = lane >> 4, l15 = lane & 15;                                \
    const int wm = w >> 1, wn = w & 1;                                          \
    const int m0 = blockIdx.y * 128, c0 = blockIdx.x * 128;                     \
    const floatx4 z4 = {0.f, 0.f, 0.f, 0.f};                                    \
    floatx4 acc[4][4];                                                          \
    _Pragma("unroll") for (int i = 0; i < 4; ++i)                               \
        _Pragma("unroll") for (int j = 0; j < 4; ++j) acc[i][j] = z4;           \
    const _Float16* pA = APTR + (size_t)(m0 + w * 32 + l15) * DIM + quad * 8;   \
    const _Float16* pB = BPTR + (size_t)(c0 + w * 32 + l15) * DIM + quad * 8;   \
    gl_lds16(pA,            &Asl[0][(w * 2 + 0) * 512]);                        \
    gl_lds16(pA + 16 * DIM, &Asl[0][(w * 2 + 1) * 512]);                        \
    gl_lds16(pB,            &Bsl[0][(w * 2 + 0) * 512]);                        \
    gl_lds16(pB + 16 * DIM, &Bsl[0][(w * 2 + 1) * 512]);                        \
    for (int k0 = 0, it = 0; k0 < DIM; k0 += 32, ++it) {                        \
        const int buf = it & 1;                                                 \
        __syncthreads();                                                        \
        if (k0 + 32 < DIM) {                                                    \
            gl_lds16(pA + k0 + 32,            &Asl[buf ^ 1][(w * 2 + 0) * 512]);\
            gl_lds16(pA + k0 + 32 + 16 * DIM, &Asl[buf ^ 1][(w * 2 + 1) * 512]);\
            gl_lds16(pB + k0 + 32,            &Bsl[buf ^ 1][(w * 2 + 0) * 512]);\
            gl_lds16(pB + k0 + 32 + 16 * DIM, &Bsl[buf ^ 1][(w * 2 + 1) * 512]);\
        }                                                                       \
        half8 af[4], bf[4];                                                     \
        _Pragma("unroll") for (int i = 0; i < 4; ++i)                           \
            af[i] = *(const half8*)&Asl[buf][(wm * 4 + i) * 512 + lane * 8];    \
        _Pragma("unroll") for (int j = 0; j < 4; ++j)                           \
            bf[j] = *(const half8*)&Bsl[buf][(wn * 4 + j) * 512 + lane * 8];    \
        _Pragma("unroll") for (int i = 0; i < 4; ++i)                           \
            _Pragma("unroll") for (int j = 0; j < 4; ++j)                       \
                acc[i][j] = __builtin_amdgcn_mfma_f32_16x16x32_f16(             \
                    af[i], bf[j], acc[i][j], 0, 0, 0);                          \
    }

// KQV: N=2304 (18 blocks of 128), scatter epilogue into k/q/v f16 buffers.
__global__ __launch_bounds__(256)
void kqv_gemm2(const _Float16* __restrict__ xh, const _Float16* __restrict__ Wh,
               const float* __restrict__ bias, _Float16* __restrict__ kb,
               _Float16* __restrict__ qb, _Float16* __restrict__ vb) {
    GEMM_CORE(xh, Wh)
    #pragma unroll
    for (int j = 0; j < 4; ++j) {
        const int cbase = c0 + (wn * 4 + j) * 16;
        const int h = cbase / 192;
        const int rem = cbase - h * 192;
        const int part = rem >> 6;
        const int d = (rem & 63) + l15;
        _Float16* dst = (part == 0) ? kb : (part == 1 ? qb : vb);
        const float bv = bias[cbase + l15];
        #pragma unroll
        for (int i = 0; i < 4; ++i)
            #pragma unroll
            for (int r = 0; r < 4; ++r) {
                const int m = m0 + (wm * 4 + i) * 16 + quad * 4 + r;
                const int bidx = m >> 11, n = m & (SEQ - 1);
                dst[(((size_t)(bidx * NH + h) * SEQ + n) << 6) + d] =
                    (_Float16)(acc[i][j][r] + bv);
            }
    }
}

// Proj: N=768 (6 blocks of 128), fp32 output + bias.
__global__ __launch_bounds__(256)
void proj_gemm2(const _Float16* __restrict__ A, const _Float16* __restrict__ Wh,
                const float* __restrict__ bias, float* __restrict__ out) {
    GEMM_CORE(A, Wh)
    #pragma unroll
    for (int j = 0; j < 4; ++j) {
        const int cbase = c0 + (wn * 4 + j) * 16;
        const float bv = bias[cbase + l15];
        #pragma unroll
        for (int i = 0; i < 4; ++i)
            #pragma unroll
            for (int r = 0; r < 4; ++r) {
                const int m = m0 + (wm * 4 + i) * 16 + quad * 4 + r;
                out[(size_t)m * DIM + cbase + l15] = acc[i][j][r] + bv;
            }
    }
}

// ---------------------------------------------------------------------------
// V transpose: vb [B][H][SEQ][HD] -> vbT [B][H][HD][SEQ]  (f16)
// ---------------------------------------------------------------------------
__global__ __launch_bounds__(256)
void v_transpose(const _Float16* __restrict__ vb, _Float16* __restrict__ vbT) {
    __shared__ _Float16 T[64 * 72];
    const int t = threadIdx.x;
    const int s0 = blockIdx.x * 64;
    const size_t base = (size_t)blockIdx.y * (SEQ * HD);
    {
        const int s = t >> 2, doff = (t & 3) * 16;
        const _Float16* src = vb + base + (size_t)(s0 + s) * HD + doff;
        *(half8*)&T[s * 72 + doff]     = *(const half8*)src;
        *(half8*)&T[s * 72 + doff + 8] = *(const half8*)(src + 8);
    }
    __syncthreads();
    {
        const int d = t >> 2, soff = (t & 3) * 16;
        half8 o0, o1;
        #pragma unroll
        for (int k = 0; k < 8; ++k) o0[k] = T[(soff + k) * 72 + d];
        #pragma unroll
        for (int k = 0; k < 8; ++k) o1[k] = T[(soff + 8 + k) * 72 + d];
        _Float16* dst = vbT + base + (size_t)d * SEQ + s0 + soff;
        *(half8*)dst       = o0;
        *(half8*)(dst + 8) = o1;
    }
}

// ---------------------------------------------------------------------------
// Flash attention, MFMA, K-SPLIT (flash-decoding style).
// Block = one partition of <=8 kt-tiles for a (bh, 64-row qt tile).  Wave w
// owns a 16-row band (R5 structure).  Max-free softmax => partials combine
// by plain summation: O = sum_p O_p, l = sum_p l_p.  Single-partition tiles
// (qt < 8) finalize directly; others write f16 O-partials + fp32 l-partials.
// Critical path per block: <=8 barrier-iterations (was 32).
// ---------------------------------------------------------------------------
__global__ __launch_bounds__(256)
void attn_mfma(const _Float16* __restrict__ qb, const _Float16* __restrict__ kbuf,
               const _Float16* __restrict__ vbT, _Float16* __restrict__ sa,
               _Float16* __restrict__ Opart, float* __restrict__ lpart) {
    __shared__ _Float16 Kl[2][64 * 64];
    __shared__ _Float16 Vl[2][64 * 64];
    __shared__ _Float16 Pl[4][16 * 72];
    // decode (qt, p, np) from blockIdx.x in [0,80)
    int u = blockIdx.x, qt, p, np;
    if (u < 8)       { qt = u;                            p = 0;      np = 1; }
    else if (u < 24) { int v = u - 8;  qt = 8  + (v >> 1); p = v & 1; np = 2; }
    else if (u < 48) { int v = u - 24; qt = 16 + v / 3;    p = v % 3; np = 3; }
    else             { int v = u - 48; qt = 24 + (v >> 2); p = v & 3; np = 4; }
    const int kt0 = p * 8;
    const int ktn = (p == np - 1) ? (qt - kt0 + 1) : 8;   // tiles in this part

    const int bh = blockIdx.y;
    const int t = threadIdx.x, w = t >> 6, lane = t & 63, quad = lane >> 4, l15 = lane & 15;
    const size_t base = (size_t)bh * (SEQ * HD);
    const int i0 = qt * 64 + w * 16;
    _Float16* Pw = Pl[w];
    const _Float16* Kg = kbuf + base;
    const _Float16* Vg = vbT + base;

    const int lr = lane >> 3, gg = lane & 7;
    const int gs = (gg ^ (lr & 7)) * 8;

    half8 aq[2];
    aq[0] = *(const half8*)(qb + base + (size_t)(i0 + l15) * HD + quad * 8);
    aq[1] = *(const half8*)(qb + base + (size_t)(i0 + l15) * HD + 32 + quad * 8);
    #pragma unroll
    for (int k = 0; k < 8; ++k) {           // fold 1/sqrt(HD) into Q
        aq[0][k] = aq[0][k] * (_Float16)0.125f;
        aq[1][k] = aq[1][k] * (_Float16)0.125f;
    }

    const floatx4 z4 = {0.f, 0.f, 0.f, 0.f};
    floatx4 O[4];
    #pragma unroll
    for (int dt = 0; dt < 4; ++dt) O[dt] = z4;
    float l_part[4] = {0.f, 0.f, 0.f, 0.f};

    // prologue: stage first tile into buffer 0
    #pragma unroll
    for (int pp = 0; pp < 2; ++pp) {
        const int c = w * 2 + pp, row = c * 8 + lr;
        gl_lds16(Kg + (size_t)(kt0 * 64 + row) * HD + gs,  &Kl[0][c * 512]);
        gl_lds16(Vg + (size_t)row * SEQ + kt0 * 64 + gs,   &Vl[0][c * 512]);
    }

    const int swz = l15 & 7;

    for (int it = 0; it < ktn; ++it) {
        const int kt = kt0 + it;
        const int buf = it & 1;
        const int j0 = kt * 64;
        __syncthreads();   // staging of `buf` drained; prev compute on buf^1 done

        if (it + 1 < ktn) {
            const _Float16* Kn = Kg + (size_t)(j0 + 64) * HD;
            const _Float16* Vn = Vg + (j0 + 64);
            #pragma unroll
            for (int pp = 0; pp < 2; ++pp) {
                const int c = w * 2 + pp, row = c * 8 + lr;
                gl_lds16(Kn + (size_t)row * HD + gs,  &Kl[buf ^ 1][c * 512]);
                gl_lds16(Vn + (size_t)row * SEQ + gs, &Vl[buf ^ 1][c * 512]);
            }
        }

        floatx4 S[4];
        #pragma unroll
        for (int nt = 0; nt < 4; ++nt) S[nt] = z4;
        #pragma unroll
        for (int ks = 0; ks < 2; ++ks)
            #pragma unroll
            for (int nt = 0; nt < 4; ++nt) {
                half8 bk = *(const half8*)&Kl[buf][(nt * 16 + l15) * 64 +
                                                   (((ks * 4 + quad) ^ swz) << 3)];
                S[nt] = __builtin_amdgcn_mfma_f32_16x16x32_f16(aq[ks], bk, S[nt], 0, 0, 0);
            }

        const bool diag = (kt == qt);
        asm volatile("" ::: "memory");   // WAR: prior P-frag reads before new writes
        #pragma unroll
        for (int nt = 0; nt < 4; ++nt) {
            const int j = j0 + nt * 16 + l15;
            #pragma unroll
            for (int r = 0; r < 4; ++r) {
                float pv = __expf(S[nt][r]);
                if (diag && j > (i0 + quad * 4 + r)) pv = 0.f;
                l_part[r] += pv;
                Pw[(quad * 4 + r) * 72 + nt * 16 + l15] = (_Float16)pv;
            }
        }
        asm volatile("" ::: "memory");   // RAW: P writes before fragment reads
        #pragma unroll
        for (int ks = 0; ks < 2; ++ks) {
            half8 ap = *(const half8*)&Pw[l15 * 72 + ks * 32 + quad * 8];
            #pragma unroll
            for (int dt = 0; dt < 4; ++dt) {
                half8 bv = *(const half8*)&Vl[buf][(dt * 16 + l15) * 64 +
                                                    (((ks * 4 + quad) ^ swz) << 3)];
                O[dt] = __builtin_amdgcn_mfma_f32_16x16x32_f16(ap, bv, O[dt], 0, 0, 0);
            }
        }
    }

    if (np == 1) {
        // finalize directly into sa
        const int bidx = bh / NH, h = bh - bidx * NH;
        #pragma unroll
        for (int r = 0; r < 4; ++r) {
            float rs = l_part[r];
            #pragma unroll
            for (int off = 1; off < 16; off <<= 1) rs += __shfl_xor(rs, off);
            const float inv = 1.0f / rs;
            const int i = i0 + quad * 4 + r;
            #pragma unroll
            for (int dt = 0; dt < 4; ++dt)
                sa[(size_t)(bidx * SEQ + i) * DIM + h * HD + dt * 16 + l15] =
                    (_Float16)(O[dt][r] * inv);
        }
    } else {
        // write partials: O (f16) and l (fp32), slot (bh, qt, p)
        const size_t slot = ((size_t)(bh * 32 + qt) * 4 + p);
        _Float16* Od = Opart + slot * 4096;
        float*    ld = lpart + slot * 64;
        #pragma unroll
        for (int r = 0; r < 4; ++r) {
            float rs = l_part[r];
            #pragma unroll
            for (int off = 1; off < 16; off <<= 1) rs += __shfl_xor(rs, off);
            const int row = w * 16 + quad * 4 + r;
            ld[row] = rs;                       // 16 lanes write same value
            #pragma unroll
            for (int dt = 0; dt < 4; ++dt)
                Od[row * 64 + dt * 16 + l15] = (_Float16)O[dt][r];
        }
    }
}

// ---------------------------------------------------------------------------
// Combine K-split partials: sa = (sum_p O_p) / (sum_p l_p) for qt >= 8.
// grid (24 qt-values, 24 bh), 256 threads; thread covers 16 d of one row.
// ---------------------------------------------------------------------------
__global__ __launch_bounds__(256)
void attn_combine(const _Float16* __restrict__ Opart, const float* __restrict__ lpart,
                  _Float16* __restrict__ sa) {
    const int qt = 8 + blockIdx.x;
    const int bh = blockIdx.y;
    const int np = (qt >> 3) + 1;
    const int t = threadIdx.x;
    const int row = t >> 2, d0 = (t & 3) * 16;
    const size_t slot0 = ((size_t)(bh * 32 + qt) * 4);

    float lsum = 0.f;
    for (int p = 0; p < np; ++p) lsum += lpart[(slot0 + p) * 64 + row];

    float acc[16];
    #pragma unroll
    for (int k = 0; k < 16; ++k) acc[k] = 0.f;
    for (int p = 0; p < np; ++p) {
        const _Float16* src = Opart + (slot0 + p) * 4096 + row * 64 + d0;
        half8 a = *(const half8*)src;
        half8 b = *(const half8*)(src + 8);
        #pragma unroll
        for (int k = 0; k < 8; ++k) { acc[k] += (float)a[k]; acc[8 + k] += (float)b[k]; }
    }
    const float inv = 1.0f / lsum;
    const int bidx = bh / NH, h = bh - bidx * NH;
    _Float16* dst = sa + (size_t)(bidx * SEQ + qt * 64 + row) * DIM + h * HD + d0;
    half8 o0, o1;
    #pragma unroll
    for (int k = 0; k < 8; ++k) { o0[k] = (_Float16)(acc[k] * inv); o1[k] = (_Float16)(acc[8 + k] * inv); }
    *(half8*)dst       = o0;
    *(half8*)(dst + 8) = o1;
}

// ---------------------------------------------------------------------------
extern "C" void kernel_launch(void* const* d_in, const int* in_sizes, int n_in,
                              void* d_out, int out_size, void* d_ws, size_t ws_size,
                              hipStream_t stream) {
    (void)in_sizes; (void)n_in; (void)out_size; (void)ws_size;
    const float* x  = (const float*)d_in[0];
    const float* Wk = (const float*)d_in[1];
    const float* bk = (const float*)d_in[2];
    const float* Wp = (const float*)d_in[3];
    const float* bp = (const float*)d_in[4];
    float* out = (float*)d_out;

    _Float16* ws = (_Float16*)d_ws;
    const size_t per = (size_t)BB * NH * SEQ * HD;          // 3,145,728 halves
    const int nx = BB * SEQ * DIM;                          // 3,145,728
    const int nwk = NH * 3 * HD * DIM;                      // 1,769,472
    const int nwp = DIM * DIM;                              //   589,824
    _Float16* kb  = ws;
    _Float16* qb  = ws + per;
    _Float16* vb  = ws + 2 * per;
    _Float16* vbT = ws + 3 * per;
    _Float16* sa  = ws + 4 * per;
    _Float16* xh  = ws + 5 * per;
    _Float16* Wkh = xh + nx;
    _Float16* Wph = Wkh + nwk;
    _Float16* Opart = Wph + nwp;                            // 24*32*4*4096 f16
    float*    lpart = (float*)(Opart + (size_t)24 * 32 * 4 * 4096);

    const int nb0 = nx / 2048, nb1 = nwk / 2048, nb2 = nwp / 2048;
    cvt3<<<dim3(nb0 + nb1 + nb2), 256, 0, stream>>>(x, xh, nb0, Wk, Wkh, nb1, Wp, Wph);

    kqv_gemm2  <<<dim3(18, 32), 256, 0, stream>>>(xh, Wkh, bk, kb, qb, vb);
    v_transpose<<<dim3(32, 24), 256, 0, stream>>>(vb, vbT);
    attn_mfma  <<<dim3(80, 24), 256, 0, stream>>>(qb, kb, vbT, sa, Opart, lpart);
    attn_combine<<<dim3(24, 24), 256, 0, stream>>>(Opart, lpart, sa);
    proj_gemm2 <<<dim3(6, 32), 256, 0, stream>>>(sa, Wph, bp, out);
}

// Round 9
// 184.856 us; speedup vs baseline: 1.1642x; 1.0219x over previous
//
#include <hip/hip_runtime.h>

#define BB 2
#define SEQ 2048
#define DIM 768
#define NH 12
#define HD 64

typedef _Float16 half8 __attribute__((ext_vector_type(8)));
typedef float floatx4 __attribute__((ext_vector_type(4)));

// Async global->LDS DMA, 16 B per lane; LDS dest = wave-uniform base + lane*16.
__device__ __forceinline__ void gl_lds16(const _Float16* g, _Float16* l) {
    __builtin_amdgcn_global_load_lds(
        (const __attribute__((address_space(1))) void*)g,
        (__attribute__((address_space(3))) void*)l, 16, 0, 0);
}

// ---------------------------------------------------------------------------
// One-shot fp32 -> f16 convert for x, W_kqv, W_proj (block ranges).
// ---------------------------------------------------------------------------
__global__ __launch_bounds__(256)
void cvt3(const float* __restrict__ s0, _Float16* __restrict__ d0, int nb0,
          const float* __restrict__ s1, _Float16* __restrict__ d1, int nb1,
          const float* __restrict__ s2, _Float16* __restrict__ d2) {
    int b = blockIdx.x;
    const float* s; _Float16* d;
    if (b < nb0)            { s = s0; d = d0; }
    else if (b < nb0 + nb1) { s = s1; d = d1; b -= nb0; }
    else                    { s = s2; d = d2; b -= nb0 + nb1; }
    const int i = (b * 256 + threadIdx.x) * 8;
    float4 a = *(const float4*)(s + i);
    float4 c = *(const float4*)(s + i + 4);
    half8 h;
    h[0] = (_Float16)a.x; h[1] = (_Float16)a.y; h[2] = (_Float16)a.z; h[3] = (_Float16)a.w;
    h[4] = (_Float16)c.x; h[5] = (_Float16)c.y; h[6] = (_Float16)c.z; h[7] = (_Float16)c.w;
    *(half8*)(d + i) = h;
}

// ---------------------------------------------------------------------------
// Double-buffered m97-style GEMM core: BM=BN=128, BK=32, 4 waves (2x2).
// ---------------------------------------------------------------------------
#define GEMM_CORE(APTR, BPTR)                                                   \
    __shared__ _Float16 Asl[2][128 * 32];                                       \
    __shared__ _Float16 Bsl[2][128 * 32];                                       \
    const int t = threadIdx.x, w = t >> 6, lane = t & 63;                       \
    const int quad = lane >> 4, l15 = lane & 15;                                \
    const int wm = w >> 1, wn = w & 1;                                          \
    const int m0 = blockIdx.y * 128, c0 = blockIdx.x * 128;                     \
    const floatx4 z4 = {0.f, 0.f, 0.f, 0.f};                                    \
    floatx4 acc[4][4];                                                          \
    _Pragma("unroll") for (int i = 0; i < 4; ++i)                               \
        _Pragma("unroll") for (int j = 0; j < 4; ++j) acc[i][j] = z4;           \
    const _Float16* pA = APTR + (size_t)(m0 + w * 32 + l15) * DIM + quad * 8;   \
    const _Float16* pB = BPTR + (size_t)(c0 + w * 32 + l15) * DIM + quad * 8;   \
    gl_lds16(pA,            &Asl[0][(w * 2 + 0) * 512]);                        \
    gl_lds16(pA + 16 * DIM, &Asl[0][(w * 2 + 1) * 512]);                        \
    gl_lds16(pB,            &Bsl[0][(w * 2 + 0) * 512]);                        \
    gl_lds16(pB + 16 * DIM, &Bsl[0][(w * 2 + 1) * 512]);                        \
    for (int k0 = 0, it = 0; k0 < DIM; k0 += 32, ++it) {                        \
        const int buf = it & 1;                                                 \
        __syncthreads();                                                        \
        if (k0 + 32 < DIM) {                                                    \
            gl_lds16(pA + k0 + 32,            &Asl[buf ^ 1][(w * 2 + 0) * 512]);\
            gl_lds16(pA + k0 + 32 + 16 * DIM, &Asl[buf ^ 1][(w * 2 + 1) * 512]);\
            gl_lds16(pB + k0 + 32,            &Bsl[buf ^ 1][(w * 2 + 0) * 512]);\
            gl_lds16(pB + k0 + 32 + 16 * DIM, &Bsl[buf ^ 1][(w * 2 + 1) * 512]);\
        }                                                                       \
        half8 af[4], bf[4];                                                     \
        _Pragma("unroll") for (int i = 0; i < 4; ++i)                           \
            af[i] = *(const half8*)&Asl[buf][(wm * 4 + i) * 512 + lane * 8];    \
        _Pragma("unroll") for (int j = 0; j < 4; ++j)                           \
            bf[j] = *(const half8*)&Bsl[buf][(wn * 4 + j) * 512 + lane * 8];    \
        _Pragma("unroll") for (int i = 0; i < 4; ++i)                           \
            _Pragma("unroll") for (int j = 0; j < 4; ++j)                       \
                acc[i][j] = __builtin_amdgcn_mfma_f32_16x16x32_f16(             \
                    af[i], bf[j], acc[i][j], 0, 0, 0);                          \
    }

// KQV: N=2304 (18 blocks of 128), scatter epilogue into k/q/v f16 buffers.
__global__ __launch_bounds__(256)
void kqv_gemm2(const _Float16* __restrict__ xh, const _Float16* __restrict__ Wh,
               const float* __restrict__ bias, _Float16* __restrict__ kb,
               _Float16* __restrict__ qb, _Float16* __restrict__ vb) {
    GEMM_CORE(xh, Wh)
    #pragma unroll
    for (int j = 0; j < 4; ++j) {
        const int cbase = c0 + (wn * 4 + j) * 16;
        const int h = cbase / 192;
        const int rem = cbase - h * 192;
        const int part = rem >> 6;
        const int d = (rem & 63) + l15;
        _Float16* dst = (part == 0) ? kb : (part == 1 ? qb : vb);
        const float bv = bias[cbase + l15];
        #pragma unroll
        for (int i = 0; i < 4; ++i)
            #pragma unroll
            for (int r = 0; r < 4; ++r) {
                const int m = m0 + (wm * 4 + i) * 16 + quad * 4 + r;
                const int bidx = m >> 11, n = m & (SEQ - 1);
                dst[(((size_t)(bidx * NH + h) * SEQ + n) << 6) + d] =
                    (_Float16)(acc[i][j][r] + bv);
            }
    }
}

// Proj: N=768 (6 blocks of 128), fp32 output + bias.
__global__ __launch_bounds__(256)
void proj_gemm2(const _Float16* __restrict__ A, const _Float16* __restrict__ Wh,
                const float* __restrict__ bias, float* __restrict__ out) {
    GEMM_CORE(A, Wh)
    #pragma unroll
    for (int j = 0; j < 4; ++j) {
        const int cbase = c0 + (wn * 4 + j) * 16;
        const float bv = bias[cbase + l15];
        #pragma unroll
        for (int i = 0; i < 4; ++i)
            #pragma unroll
            for (int r = 0; r < 4; ++r) {
                const int m = m0 + (wm * 4 + i) * 16 + quad * 4 + r;
                out[(size_t)m * DIM + cbase + l15] = acc[i][j][r] + bv;
            }
    }
}

// ---------------------------------------------------------------------------
// V transpose: vb [B][H][SEQ][HD] -> vbT [B][H][HD][SEQ]  (f16)
// ---------------------------------------------------------------------------
__global__ __launch_bounds__(256)
void v_transpose(const _Float16* __restrict__ vb, _Float16* __restrict__ vbT) {
    __shared__ _Float16 T[64 * 72];
    const int t = threadIdx.x;
    const int s0 = blockIdx.x * 64;
    const size_t base = (size_t)blockIdx.y * (SEQ * HD);
    {
        const int s = t >> 2, doff = (t & 3) * 16;
        const _Float16* src = vb + base + (size_t)(s0 + s) * HD + doff;
        *(half8*)&T[s * 72 + doff]     = *(const half8*)src;
        *(half8*)&T[s * 72 + doff + 8] = *(const half8*)(src + 8);
    }
    __syncthreads();
    {
        const int d = t >> 2, soff = (t & 3) * 16;
        half8 o0, o1;
        #pragma unroll
        for (int k = 0; k < 8; ++k) o0[k] = T[(soff + k) * 72 + d];
        #pragma unroll
        for (int k = 0; k < 8; ++k) o1[k] = T[(soff + 8 + k) * 72 + d];
        _Float16* dst = vbT + base + (size_t)d * SEQ + s0 + soff;
        *(half8*)dst       = o0;
        *(half8*)(dst + 8) = o1;
    }
}

// ---------------------------------------------------------------------------
// Flash attention, MFMA, K-SPLIT.  exp2 with log2e folded into Q scale;
// uniform diagonal branch (non-diag tiles emit no mask ops); P buffer
// stride 64 with XOR granule swizzle (write g^=row&7, read c^=l15&7) ->
// LDS = 40960 B exactly = 4 blocks/CU ceiling.
// ---------------------------------------------------------------------------
__global__ __launch_bounds__(256)
void attn_mfma(const _Float16* __restrict__ qb, const _Float16* __restrict__ kbuf,
               const _Float16* __restrict__ vbT, _Float16* __restrict__ sa,
               _Float16* __restrict__ Opart, float* __restrict__ lpart) {
    __shared__ _Float16 Kl[2][64 * 64];
    __shared__ _Float16 Vl[2][64 * 64];
    __shared__ _Float16 Pl[4][16 * 64];
    // decode (qt, p, np) from blockIdx.x in [0,80)
    int u = blockIdx.x, qt, p, np;
    if (u < 8)       { qt = u;                            p = 0;      np = 1; }
    else if (u < 24) { int v = u - 8;  qt = 8  + (v >> 1); p = v & 1; np = 2; }
    else if (u < 48) { int v = u - 24; qt = 16 + v / 3;    p = v % 3; np = 3; }
    else             { int v = u - 48; qt = 24 + (v >> 2); p = v & 3; np = 4; }
    const int kt0 = p * 8;
    const int ktn = (p == np - 1) ? (qt - kt0 + 1) : 8;   // tiles in this part

    const int bh = blockIdx.y;
    const int t = threadIdx.x, w = t >> 6, lane = t & 63, quad = lane >> 4, l15 = lane & 15;
    const size_t base = (size_t)bh * (SEQ * HD);
    const int i0 = qt * 64 + w * 16;
    _Float16* Pw = Pl[w];
    const _Float16* Kg = kbuf + base;
    const _Float16* Vg = vbT + base;

    const int lr = lane >> 3, gg = lane & 7;
    const int gs = (gg ^ (lr & 7)) * 8;

    half8 aq[2];
    aq[0] = *(const half8*)(qb + base + (size_t)(i0 + l15) * HD + quad * 8);
    aq[1] = *(const half8*)(qb + base + (size_t)(i0 + l15) * HD + 32 + quad * 8);
    // fold 1/sqrt(HD) * log2(e) into Q: p = exp2(S)
    const _Float16 qs = (_Float16)(0.125f * 1.44269504f);
    #pragma unroll
    for (int k = 0; k < 8; ++k) { aq[0][k] *= qs; aq[1][k] *= qs; }

    const floatx4 z4 = {0.f, 0.f, 0.f, 0.f};
    floatx4 O[4];
    #pragma unroll
    for (int dt = 0; dt < 4; ++dt) O[dt] = z4;
    float l_part[4] = {0.f, 0.f, 0.f, 0.f};

    // prologue: stage first tile into buffer 0
    #pragma unroll
    for (int pp = 0; pp < 2; ++pp) {
        const int c = w * 2 + pp, row = c * 8 + lr;
        gl_lds16(Kg + (size_t)(kt0 * 64 + row) * HD + gs,  &Kl[0][c * 512]);
        gl_lds16(Vg + (size_t)row * SEQ + kt0 * 64 + gs,   &Vl[0][c * 512]);
    }

    const int swz = l15 & 7;
    const int prow = quad * 4;                 // P write rows base (this lane)

    for (int it = 0; it < ktn; ++it) {
        const int kt = kt0 + it;
        const int buf = it & 1;
        const int j0 = kt * 64;
        __syncthreads();   // staging of `buf` drained; prev compute on buf^1 done

        if (it + 1 < ktn) {
            const _Float16* Kn = Kg + (size_t)(j0 + 64) * HD;
            const _Float16* Vn = Vg + (j0 + 64);
            #pragma unroll
            for (int pp = 0; pp < 2; ++pp) {
                const int c = w * 2 + pp, row = c * 8 + lr;
                gl_lds16(Kn + (size_t)row * HD + gs,  &Kl[buf ^ 1][c * 512]);
                gl_lds16(Vn + (size_t)row * SEQ + gs, &Vl[buf ^ 1][c * 512]);
            }
        }

        floatx4 S[4];
        #pragma unroll
        for (int nt = 0; nt < 4; ++nt) S[nt] = z4;
        #pragma unroll
        for (int ks = 0; ks < 2; ++ks)
            #pragma unroll
            for (int nt = 0; nt < 4; ++nt) {
                half8 bk = *(const half8*)&Kl[buf][(nt * 16 + l15) * 64 +
                                                   (((ks * 4 + quad) ^ swz) << 3)];
                S[nt] = __builtin_amdgcn_mfma_f32_16x16x32_f16(aq[ks], bk, S[nt], 0, 0, 0);
            }

        asm volatile("" ::: "memory");   // WAR: prior P-frag reads before new writes
        // P store: element (row, col) -> row*64 + ((col>>3)^(row&7))*8 + (col&7)
        if (kt == qt) {                  // diagonal tile: masked path
            #pragma unroll
            for (int nt = 0; nt < 4; ++nt) {
                const int j = j0 + nt * 16 + l15;
                #pragma unroll
                for (int r = 0; r < 4; ++r) {
                    float pv = exp2f(S[nt][r]);
                    if (j > (i0 + prow + r)) pv = 0.f;
                    l_part[r] += pv;
                    const int row = prow + r, col = nt * 16 + l15;
                    Pw[row * 64 + ((((col >> 3) ^ (row & 7))) << 3) + (col & 7)] = (_Float16)pv;
                }
            }
        } else {                         // interior tile: no masking ops
            #pragma unroll
            for (int nt = 0; nt < 4; ++nt) {
                #pragma unroll
                for (int r = 0; r < 4; ++r) {
                    float pv = exp2f(S[nt][r]);
                    l_part[r] += pv;
                    const int row = prow + r, col = nt * 16 + l15;
                    Pw[row * 64 + ((((col >> 3) ^ (row & 7))) << 3) + (col & 7)] = (_Float16)pv;
                }
            }
        }
        asm volatile("" ::: "memory");   // RAW: P writes before fragment reads
        #pragma unroll
        for (int ks = 0; ks < 2; ++ks) {
            half8 ap = *(const half8*)&Pw[l15 * 64 + (((ks * 4 + quad) ^ swz) << 3)];
            #pragma unroll
            for (int dt = 0; dt < 4; ++dt) {
                half8 bv = *(const half8*)&Vl[buf][(dt * 16 + l15) * 64 +
                                                    (((ks * 4 + quad) ^ swz) << 3)];
                O[dt] = __builtin_amdgcn_mfma_f32_16x16x32_f16(ap, bv, O[dt], 0, 0, 0);
            }
        }
    }

    if (np == 1) {
        // finalize directly into sa
        const int bidx = bh / NH, h = bh - bidx * NH;
        #pragma unroll
        for (int r = 0; r < 4; ++r) {
            float rs = l_part[r];
            #pragma unroll
            for (int off = 1; off < 16; off <<= 1) rs += __shfl_xor(rs, off);
            const float inv = 1.0f / rs;
            const int i = i0 + quad * 4 + r;
            #pragma unroll
            for (int dt = 0; dt < 4; ++dt)
                sa[(size_t)(bidx * SEQ + i) * DIM + h * HD + dt * 16 + l15] =
                    (_Float16)(O[dt][r] * inv);
        }
    } else {
        // write partials: O (f16) and l (fp32), slot (bh, qt, p)
        const size_t slot = ((size_t)(bh * 32 + qt) * 4 + p);
        _Float16* Od = Opart + slot * 4096;
        float*    ld = lpart + slot * 64;
        #pragma unroll
        for (int r = 0; r < 4; ++r) {
            float rs = l_part[r];
            #pragma unroll
            for (int off = 1; off < 16; off <<= 1) rs += __shfl_xor(rs, off);
            const int row = w * 16 + quad * 4 + r;
            ld[row] = rs;                       // 16 lanes write same value
            #pragma unroll
            for (int dt = 0; dt < 4; ++dt)
                Od[row * 64 + dt * 16 + l15] = (_Float16)O[dt][r];
        }
    }
}

// ---------------------------------------------------------------------------
// Combine K-split partials: sa = (sum_p O_p) / (sum_p l_p) for qt >= 8.
// ---------------------------------------------------------------------------
__global__ __launch_bounds__(256)
void attn_combine(const _Float16* __restrict__ Opart, const float* __restrict__ lpart,
                  _Float16* __restrict__ sa) {
    const int qt = 8 + blockIdx.x;
    const int bh = blockIdx.y;
    const int np = (qt >> 3) + 1;
    const int t = threadIdx.x;
    const int row = t >> 2, d0 = (t & 3) * 16;
    const size_t slot0 = ((size_t)(bh * 32 + qt) * 4);

    float lsum = 0.f;
    for (int p = 0; p < np; ++p) lsum += lpart[(slot0 + p) * 64 + row];

    float acc[16];
    #pragma unroll
    for (int k = 0; k < 16; ++k) acc[k] = 0.f;
    for (int p = 0; p < np; ++p) {
        const _Float16* src = Opart + (slot0 + p) * 4096 + row * 64 + d0;
        half8 a = *(const half8*)src;
        half8 b = *(const half8*)(src + 8);
        #pragma unroll
        for (int k = 0; k < 8; ++k) { acc[k] += (float)a[k]; acc[8 + k] += (float)b[k]; }
    }
    const float inv = 1.0f / lsum;
    const int bidx = bh / NH, h = bh - bidx * NH;
    _Float16* dst = sa + (size_t)(bidx * SEQ + qt * 64 + row) * DIM + h * HD + d0;
    half8 o0, o1;
    #pragma unroll
    for (int k = 0; k < 8; ++k) { o0[k] = (_Float16)(acc[k] * inv); o1[k] = (_Float16)(acc[8 + k] * inv); }
    *(half8*)dst       = o0;
    *(half8*)(dst + 8) = o1;
}

// ---------------------------------------------------------------------------
extern "C" void kernel_launch(void* const* d_in, const int* in_sizes, int n_in,
                              void* d_out, int out_size, void* d_ws, size_t ws_size,
                              hipStream_t stream) {
    (void)in_sizes; (void)n_in; (void)out_size; (void)ws_size;
    const float* x  = (const float*)d_in[0];
    const float* Wk = (const float*)d_in[1];
    const float* bk = (const float*)d_in[2];
    const float* Wp = (const float*)d_in[3];
    const float* bp = (const float*)d_in[4];
    float* out = (float*)d_out;

    _Float16* ws = (_Float16*)d_ws;
    const size_t per = (size_t)BB * NH * SEQ * HD;          // 3,145,728 halves
    const int nx = BB * SEQ * DIM;                          // 3,145,728
    const int nwk = NH * 3 * HD * DIM;                      // 1,769,472
    const int nwp = DIM * DIM;                              //   589,824
    _Float16* kb  = ws;
    _Float16* qb  = ws + per;
    _Float16* vb  = ws + 2 * per;
    _Float16* vbT = ws + 3 * per;
    _Float16* sa  = ws + 4 * per;
    _Float16* xh  = ws + 5 * per;
    _Float16* Wkh = xh + nx;
    _Float16* Wph = Wkh + nwk;
    _Float16* Opart = Wph + nwp;                            // 24*32*4*4096 f16
    float*    lpart = (float*)(Opart + (size_t)24 * 32 * 4 * 4096);

    const int nb0 = nx / 2048, nb1 = nwk / 2048, nb2 = nwp / 2048;
    cvt3<<<dim3(nb0 + nb1 + nb2), 256, 0, stream>>>(x, xh, nb0, Wk, Wkh, nb1, Wp, Wph);

    kqv_gemm2  <<<dim3(18, 32), 256, 0, stream>>>(xh, Wkh, bk, kb, qb, vb);
    v_transpose<<<dim3(32, 24), 256, 0, stream>>>(vb, vbT);
    attn_mfma  <<<dim3(80, 24), 256, 0, stream>>>(qb, kb, vbT, sa, Opart, lpart);
    attn_combine<<<dim3(24, 24), 256, 0, stream>>>(Opart, lpart, sa);
    proj_gemm2 <<<dim3(6, 32), 256, 0, stream>>>(sa, Wph, bp, out);
}